// Round 2
// baseline (1156.395 us; speedup 1.0000x reference)
//
#include <hip/hip_runtime.h>

// ShootingBlockMNModel1 — single fused kernel, REGULAR launch (graph-safe),
// hand-rolled device-scope grid barrier (1 block/CU co-residency by capacity).
// 21 fixed-point reduce iterations (one grid barrier each; redundant per-block
// cross-reduce so theta needs no broadcast barrier), backfold recursion done
// redundantly per block from LDS-stashed sums/thetas, final pass fused.
// q/p pinned in VGPRs across the whole kernel (loaded once).
//
// ws (floats): part [21][36][NB] ; then unsigned bar counter (memset to 0/launch)

#define LR 0.25f
#define NIT 20
#define TPB 512
#define NB  256

typedef float v2f __attribute__((ext_vector_type(2)));

__device__ __forceinline__ v2f tanh2(v2f x){
    v2f e;
    e.x = __expf(x.x + x.x);
    e.y = __expf(x.y + x.y);
    v2f d = e + 1.0f;
    v2f r;
    r.x = __builtin_amdgcn_rcpf(d.x);
    r.y = __builtin_amdgcn_rcpf(d.y);
    return 1.0f - (r + r);
}

// wave64 sum via DPP on the VALU pipe; result valid in lane 63
#define DPP_ADD(x, ctrl) ((x) + __int_as_float(__builtin_amdgcn_update_dpp(0, __float_as_int(x), (ctrl), 0xF, 0xF, true)))
__device__ __forceinline__ float wave_sum64(float x){
    x = DPP_ADD(x, 0x111);   // row_shr:1
    x = DPP_ADD(x, 0x112);   // row_shr:2
    x = DPP_ADD(x, 0x114);   // row_shr:4
    x = DPP_ADD(x, 0x118);   // row_shr:8  -> lane 15+16r = row sum
    x = DPP_ADD(x, 0x142);   // row_bcast:15
    x = DPP_ADD(x, 0x143);   // row_bcast:31 -> lane 63 = total
    return x;
}

// grid barrier: release fence -> arrive -> bounded spin -> acquire fence.
// Requires all gridDim.x blocks co-resident (1 block/CU here).
__device__ __forceinline__ void gbar(unsigned* cnt, unsigned target){
    __threadfence();              // flush this thread's global writes (device scope)
    __syncthreads();
    if(threadIdx.x == 0){
        __hip_atomic_fetch_add(cnt, 1u, __ATOMIC_RELAXED, __HIP_MEMORY_SCOPE_AGENT);
        int guard = 0;
        while(__hip_atomic_load(cnt, __ATOMIC_RELAXED, __HIP_MEMORY_SCOPE_AGENT) < target){
            __builtin_amdgcn_s_sleep(2);
            if(++guard > (1<<18)) break;   // watchdog: degrade to wrong-answer, never hang
        }
        __threadfence();          // invalidate L1/L2 before re-reading remote data
    }
    __syncthreads();
}

__device__ __forceinline__ void compute_grad(const float* s, const float* th,
                                             const float* ksym, const float* ksymb,
                                             float c, float* g){
    const float Ivec[4]={1.f,0.f,0.f,1.f};
    #pragma unroll
    for(int j=0;j<4;j++){
        float kv=0.f;
        #pragma unroll
        for(int m=0;m<4;m++) kv += ksym[j*4+m]*th[m];
        g[j] = kv - c*s[j];
    }
    #pragma unroll
    for(int i2=0;i2<2;i2++)
        g[4+i2] = ksymb[i2*2+0]*th[4] + ksymb[i2*2+1]*th[5] - c*s[4+i2];
    #pragma unroll
    for(int j=0;j<4;j++){
        float kv=0.f;
        #pragma unroll
        for(int m=0;m<4;m++) kv += ksym[j*4+m]*(th[6+m]-Ivec[m]);
        g[6+j] = kv - c*s[6+j];
    }
    #pragma unroll
    for(int i2=0;i2<2;i2++)
        g[10+i2] = ksymb[i2*2+0]*th[10] + ksymb[i2*2+1]*th[11] - c*s[10+i2];
}

// packed accumulate: float4 = 2 samples in v2f lanes
__device__ __forceinline__ void accum_sample2(v2f Q0, v2f Q1, v2f P0, v2f P1,
    float t1_00,float t1_01,float t1_10,float t1_11,
    float t2_00,float t2_01,float t2_10,float t2_11,float b2_0,float b2_1,
    v2f (&acc)[36]){
    v2f u0 = t2_00*Q0 + t2_01*Q1 + b2_0;
    v2f u1 = t2_10*Q0 + t2_11*Q1 + b2_1;
    v2f h0 = tanh2(u0), h1 = tanh2(u1);
    v2f s0 = 1.0f - h0*h0, s1 = 1.0f - h1*h1;
    v2f a0 = t1_00*P0 + t1_10*P1;
    v2f a1 = t1_01*P0 + t1_11*P1;
    v2f w0 = a0*s0, w1 = a1*s1;
    v2f r0 = -2.0f*(a0*h0)*s0, r1 = -2.0f*(a1*h1)*s1;
    acc[0]+=P0*h0; acc[1]+=P0*h1; acc[2]+=P1*h0; acc[3]+=P1*h1;
    acc[4]+=P0;    acc[5]+=P1;
    acc[6]+=w0*Q0; acc[7]+=w0*Q1; acc[8]+=w1*Q0; acc[9]+=w1*Q1;
    acc[10]+=w0;   acc[11]+=w1;
    v2f ps00=P0*s0, ps01=P0*s1, ps10=P1*s0, ps11=P1*s1;
    acc[12]+=ps00*Q0; acc[13]+=ps00*Q1; acc[14]+=ps01*Q0; acc[15]+=ps01*Q1;
    acc[16]+=ps10*Q0; acc[17]+=ps10*Q1; acc[18]+=ps11*Q0; acc[19]+=ps11*Q1;
    acc[20]+=ps00; acc[21]+=ps01; acc[22]+=ps10; acc[23]+=ps11;
    v2f r0q0=r0*Q0, r1q0=r1*Q0;
    acc[24]+=r0q0*Q0; acc[25]+=r0q0*Q1; acc[26]+=r0*(Q1*Q1);
    acc[27]+=r1q0*Q0; acc[28]+=r1q0*Q1; acc[29]+=r1*(Q1*Q1);
    acc[30]+=r0q0; acc[31]+=r0*Q1; acc[32]+=r1q0; acc[33]+=r1*Q1;
    acc[34]+=r0; acc[35]+=r1;
}

__device__ __forceinline__ void bk_step2(v2f Q0, v2f Q1, v2f P0, v2f P1,
    float t1_00,float t1_01,float t1_10,float t1_11,
    float t2_00,float t2_01,float t2_10,float t2_11,float b2_0,float b2_1,
    float L1_00,float L1_01,float L1_10,float L1_11,
    float L2_00,float L2_01,float L2_10,float L2_11,float lb2_0,float lb2_1,
    v2f &B0, v2f &B1){
    v2f u0 = t2_00*Q0 + t2_01*Q1 + b2_0;
    v2f u1 = t2_10*Q0 + t2_11*Q1 + b2_1;
    v2f h0 = tanh2(u0), h1 = tanh2(u1);
    v2f s0 = 1.0f - h0*h0, s1 = 1.0f - h1*h1;
    v2f a0 = t1_00*P0 + t1_10*P1;
    v2f a1 = t1_01*P0 + t1_11*P1;
    v2f w0 = a0*s0, w1 = a1*s1;
    v2f r0 = -2.0f*(a0*h0)*s0, r1 = -2.0f*(a1*h1)*s1;
    v2f lp0 = L1_00*P0 + L1_10*P1;
    v2f lp1 = L1_01*P0 + L1_11*P1;
    v2f z0 = L2_00*Q0 + L2_01*Q1 + lb2_0;
    v2f z1 = L2_10*Q0 + L2_11*Q1 + lb2_1;
    v2f m0 = lp0*s0 + r0*z0;
    v2f m1 = lp1*s1 + r1*z1;
    B0 += t2_00*m0 + t2_10*m1 + L2_00*w0 + L2_10*w1;
    B1 += t2_01*m0 + t2_11*m1 + L2_01*w0 + L2_11*w1;
}

__global__ __launch_bounds__(TPB, 2) void k_all(
    const float4* __restrict__ q4, const float4* __restrict__ p4,
    const float4* __restrict__ x4, int nv4,
    const float* __restrict__ t1i, const float* __restrict__ b1i,
    const float* __restrict__ t2i, const float* __restrict__ b2i,
    const float* __restrict__ invK, const float* __restrict__ invKb,
    float* __restrict__ part,            // [NIT+1][36][NB]
    unsigned* __restrict__ bar,          // grid barrier counter (zeroed per launch)
    float4* __restrict__ oq, float4* __restrict__ op, float4* __restrict__ ox,
    float c)
{
    const int tid  = threadIdx.x;
    const int bid  = blockIdx.x;
    const int NT   = gridDim.x * TPB;
    const int gtid = bid*TPB + tid;
    const int wave = tid >> 6, lane = tid & 63;

    __shared__ float ths[12];                  // current theta
    __shared__ float thetaAll[(NIT+1)*12];     // theta stash (all iterations)
    __shared__ float sAll[(NIT+1)*36];         // sums stash (all iterations)
    __shared__ float red[TPB/64][36];
    __shared__ float ks[16], ksb[4];
    __shared__ float4 pkS[NIT*5];              // packed theta_k + lam_{k+1}

    if(tid < 16) ks[tid]  = 0.5f*(invK[tid]  + invK[(tid&3)*4 + (tid>>2)]);
    if(tid < 4)  ksb[tid] = 0.5f*(invKb[tid] + invKb[(tid&1)*2 + (tid>>1)]);
    if(tid < 12){
        float v = (tid<4)? t1i[tid] : (tid<6)? b1i[tid-4]
                : (tid<10)? t2i[tid-6] : b2i[tid-10];
        ths[tid] = v;
        thetaAll[tid] = v;
    }
    __syncthreads();

    // Pin this thread's samples in registers for the whole kernel.
    const bool fast = (nv4 == 4*NT);
    float4 qd[4], pd[4];
    if(fast){
        #pragma unroll
        for(int sl=0; sl<4; sl++){ qd[sl]=q4[gtid + sl*NT]; pd[sl]=p4[gtid + sl*NT]; }
    }

    for(int k=0; k<=NIT; k++){
        const float t1_00=ths[0], t1_01=ths[1], t1_10=ths[2], t1_11=ths[3];
        const float t2_00=ths[6], t2_01=ths[7], t2_10=ths[8], t2_11=ths[9];
        const float b2_0=ths[10], b2_1=ths[11];

        v2f acc[36];
        #pragma unroll
        for(int j=0;j<36;j++) acc[j] = (v2f){0.f, 0.f};

        if(fast){
            #pragma unroll
            for(int sl=0; sl<4; sl++){
                v2f Q0={qd[sl].x,qd[sl].z}, Q1={qd[sl].y,qd[sl].w};
                v2f P0={pd[sl].x,pd[sl].z}, P1={pd[sl].y,pd[sl].w};
                accum_sample2(Q0,Q1,P0,P1,
                    t1_00,t1_01,t1_10,t1_11,t2_00,t2_01,t2_10,t2_11,b2_0,b2_1,acc);
            }
        }else{
            for(int j = gtid; j < nv4; j += NT){
                float4 qq = q4[j], pp = p4[j];
                v2f Q0={qq.x,qq.z}, Q1={qq.y,qq.w};
                v2f P0={pp.x,pp.z}, P1={pp.y,pp.w};
                accum_sample2(Q0,Q1,P0,P1,
                    t1_00,t1_01,t1_10,t1_11,t2_00,t2_01,t2_10,t2_11,b2_0,b2_1,acc);
            }
        }

        // wave reduction on the VALU pipe, block partials
        float wres[36];
        #pragma unroll
        for(int j=0;j<36;j++) wres[j] = wave_sum64(acc[j].x + acc[j].y);
        if(lane == 63){
            #pragma unroll
            for(int j=0;j<36;j++) red[wave][j] = wres[j];
        }
        __syncthreads();
        if(tid < 36){
            float sum = 0.f;
            #pragma unroll
            for(int w=0; w<TPB/64; w++) sum += red[w][tid];
            part[(size_t)k*36*NB + tid*NB + bid] = sum;
        }

        gbar(bar, (unsigned)(k+1)*NB);

        // redundant cross-block reduce into this block's LDS (no 2nd barrier needed)
        {
            float pv[5];
            #pragma unroll
            for(int i=0;i<5;i++){
                int j = wave + i*(TPB/64);
                if(j < 36){
                    const float* base = part + (size_t)k*36*NB + (size_t)j*NB;
                    pv[i] = base[lane] + base[lane+64] + base[lane+128] + base[lane+192];
                }else pv[i] = 0.f;
            }
            #pragma unroll
            for(int i=0;i<5;i++){
                int j = wave + i*(TPB/64);
                if(j < 36){
                    float s = wave_sum64(pv[i]);
                    if(lane == 63) sAll[k*36 + j] = s;
                }
            }
        }
        __syncthreads();

        if(k < NIT){
            if(tid == 0){
                float g[12];
                compute_grad(sAll + k*36, thetaAll + k*12, ks, ksb, c, g);
                #pragma unroll
                for(int j=0;j<12;j++){
                    float t = thetaAll[k*12+j] - LR*g[j];
                    ths[j] = t;
                    thetaAll[(k+1)*12+j] = t;
                }
            }
            __syncthreads();
        }
    }

    // backfold: serial 12-dim adjoint recursion, redundant per block from LDS
    if(tid == 0){
        float lv[12];
        compute_grad(sAll + NIT*36, thetaAll + NIT*12, ks, ksb, c, lv);
        for(int k=NIT-1;k>=0;k--){
            const float* s = sAll + k*36;
            const float* T = thetaAll + k*12;
            float* P = (float*)&pkS[k*5];
            P[0]=T[0]; P[1]=T[1]; P[2]=T[2]; P[3]=T[3];
            P[4]=T[6]; P[5]=T[7]; P[6]=T[8]; P[7]=T[9];
            P[8]=T[10]; P[9]=T[11];
            P[10]=lv[0]; P[11]=lv[1]; P[12]=lv[2]; P[13]=lv[3];
            P[14]=lv[6]; P[15]=lv[7]; P[16]=lv[8]; P[17]=lv[9];
            P[18]=lv[10]; P[19]=lv[11];
            float H[12];
            for(int a=0;a<2;a++)for(int b=0;b<2;b++){
                int j=a*2+b;
                float data = s[12+a*4+b*2+0]*lv[6+b*2+0]
                           + s[12+a*4+b*2+1]*lv[6+b*2+1]
                           + s[20+a*2+b]*lv[10+b];
                float kv=0.f;
                for(int m=0;m<4;m++) kv += ks[j*4+m]*lv[m];
                H[j]=kv - c*data;
            }
            H[4] = ksb[0]*lv[4] + ksb[1]*lv[5];
            H[5] = ksb[2]*lv[4] + ksb[3]*lv[5];
            for(int cc=0;cc<2;cc++)for(int d=0;d<2;d++){
                int j=cc*2+d;
                float term1 = lv[0+cc]*s[12+0*4+cc*2+d] + lv[2+cc]*s[12+1*4+cc*2+d];
                float term2 = lv[6+cc*2+0]*s[24+cc*3+(0+d)] + lv[6+cc*2+1]*s[24+cc*3+(1+d)];
                float term3 = lv[10+cc]*s[30+cc*2+d];
                float kv=0.f;
                for(int m=0;m<4;m++) kv += ks[j*4+m]*lv[6+m];
                H[6+j]=kv - c*(term1+term2+term3);
            }
            for(int cc=0;cc<2;cc++){
                float z1 = lv[0+cc]*s[20+0*2+cc] + lv[2+cc]*s[20+1*2+cc];
                float z2 = lv[6+cc*2+0]*s[30+cc*2+0] + lv[6+cc*2+1]*s[30+cc*2+1];
                float z3 = lv[10+cc]*s[34+cc];
                float kv = ksb[cc*2+0]*lv[10] + ksb[cc*2+1]*lv[11];
                H[10+cc]=kv - c*(z1+z2+z3);
            }
            for(int j=0;j<12;j++) lv[j] -= LR*H[j];
        }
    }
    __syncthreads();

    // final phase: theta row 20 + pk from LDS, q/p still in registers
    const float* T20 = thetaAll + NIT*12;
    const float f1_00=T20[0], f1_01=T20[1], f1_10=T20[2], f1_11=T20[3];
    const float fb1_0=T20[4], fb1_1=T20[5];
    const float f2_00=T20[6], f2_01=T20[7], f2_10=T20[8], f2_11=T20[9];
    const float fb2_0=T20[10], fb2_1=T20[11];

    if(fast){
        v2f Q0r[4],Q1r[4],P0r[4],P1r[4],B0r[4],B1r[4];
        #pragma unroll
        for(int sl=0; sl<4; sl++){
            Q0r[sl]=(v2f){qd[sl].x,qd[sl].z}; Q1r[sl]=(v2f){qd[sl].y,qd[sl].w};
            P0r[sl]=(v2f){pd[sl].x,pd[sl].z}; P1r[sl]=(v2f){pd[sl].y,pd[sl].w};
            B0r[sl]=(v2f){0.f,0.f}; B1r[sl]=(v2f){0.f,0.f};
        }
        for(int k=0;k<NIT;k++){
            float4 P0=pkS[k*5+0], P1=pkS[k*5+1], P2=pkS[k*5+2], P3=pkS[k*5+3], P4v=pkS[k*5+4];
            float t1_00=P0.x,t1_01=P0.y,t1_10=P0.z,t1_11=P0.w;
            float t2_00=P1.x,t2_01=P1.y,t2_10=P1.z,t2_11=P1.w;
            float b2_0=P2.x,b2_1=P2.y;
            float L1_00=P2.z,L1_01=P2.w,L1_10=P3.x,L1_11=P3.y;
            float L2_00=P3.z,L2_01=P3.w,L2_10=P4v.x,L2_11=P4v.y,lb2_0=P4v.z,lb2_1=P4v.w;
            #pragma unroll
            for(int sl=0; sl<4; sl++)
                bk_step2(Q0r[sl],Q1r[sl],P0r[sl],P1r[sl],
                    t1_00,t1_01,t1_10,t1_11,t2_00,t2_01,t2_10,t2_11,b2_0,b2_1,
                    L1_00,L1_01,L1_10,L1_11,L2_00,L2_01,L2_10,L2_11,lb2_0,lb2_1,
                    B0r[sl],B1r[sl]);
        }
        #pragma unroll
        for(int sl=0; sl<4; sl++){
            int j = gtid + sl*NT;
            v2f Q0=Q0r[sl], Q1=Q1r[sl], P0=P0r[sl], P1=P1r[sl];
            v2f Bs0=B0r[sl], Bs1=B1r[sl];
            v2f u0 = f2_00*Q0 + f2_01*Q1 + fb2_0;
            v2f u1 = f2_10*Q0 + f2_11*Q1 + fb2_1;
            v2f h0 = tanh2(u0), h1 = tanh2(u1);
            v2f s0 = 1.0f - h0*h0, s1 = 1.0f - h1*h1;
            v2f a0 = f1_00*P0 + f1_10*P1;
            v2f a1 = f1_01*P0 + f1_11*P1;
            v2f w0 = a0*s0, w1 = a1*s1;
            v2f dq0 = f1_00*h0 + f1_01*h1 + fb1_0;
            v2f dq1 = f1_10*h0 + f1_11*h1 + fb1_1;
            v2f dp0 = c*(LR*Bs0 - (f2_00*w0 + f2_10*w1));
            v2f dp1 = c*(LR*Bs1 - (f2_01*w0 + f2_11*w1));
            oq[j] = make_float4(dq0.x, dq1.x, dq0.y, dq1.y);
            op[j] = make_float4(dp0.x, dp1.x, dp0.y, dp1.y);
            float4 xx = x4[j];
            v2f X0={xx.x,xx.z}, X1={xx.y,xx.w};
            v2f xu0 = f2_00*X0 + f2_01*X1 + fb2_0;
            v2f xu1 = f2_10*X0 + f2_11*X1 + fb2_1;
            v2f xh0 = tanh2(xu0), xh1 = tanh2(xu1);
            v2f xd0 = f1_00*xh0 + f1_01*xh1 + fb1_0;
            v2f xd1 = f1_10*xh0 + f1_11*xh1 + fb1_1;
            ox[j] = make_float4(xd0.x, xd1.x, xd0.y, xd1.y);
        }
    }else{
        for(int j = gtid; j < nv4; j += NT){
            float4 qq=q4[j], pp=p4[j];
            v2f Q0={qq.x,qq.z}, Q1={qq.y,qq.w};
            v2f P0={pp.x,pp.z}, P1={pp.y,pp.w};
            v2f Bs0={0.f,0.f}, Bs1={0.f,0.f};
            for(int k=0;k<NIT;k++){
                float4 P0v=pkS[k*5+0], P1v=pkS[k*5+1], P2v=pkS[k*5+2], P3v=pkS[k*5+3], P4v=pkS[k*5+4];
                bk_step2(Q0,Q1,P0,P1,
                    P0v.x,P0v.y,P0v.z,P0v.w, P1v.x,P1v.y,P1v.z,P1v.w, P2v.x,P2v.y,
                    P2v.z,P2v.w,P3v.x,P3v.y, P3v.z,P3v.w,P4v.x,P4v.y,P4v.z,P4v.w,
                    Bs0,Bs1);
            }
            v2f u0 = f2_00*Q0 + f2_01*Q1 + fb2_0;
            v2f u1 = f2_10*Q0 + f2_11*Q1 + fb2_1;
            v2f h0 = tanh2(u0), h1 = tanh2(u1);
            v2f s0 = 1.0f - h0*h0, s1 = 1.0f - h1*h1;
            v2f a0 = f1_00*P0 + f1_10*P1;
            v2f a1 = f1_01*P0 + f1_11*P1;
            v2f w0 = a0*s0, w1 = a1*s1;
            v2f dq0 = f1_00*h0 + f1_01*h1 + fb1_0;
            v2f dq1 = f1_10*h0 + f1_11*h1 + fb1_1;
            v2f dp0 = c*(LR*Bs0 - (f2_00*w0 + f2_10*w1));
            v2f dp1 = c*(LR*Bs1 - (f2_01*w0 + f2_11*w1));
            oq[j] = make_float4(dq0.x, dq1.x, dq0.y, dq1.y);
            op[j] = make_float4(dp0.x, dp1.x, dp0.y, dp1.y);
            float4 xx = x4[j];
            v2f X0={xx.x,xx.z}, X1={xx.y,xx.w};
            v2f xu0 = f2_00*X0 + f2_01*X1 + fb2_0;
            v2f xu1 = f2_10*X0 + f2_11*X1 + fb2_1;
            v2f xh0 = tanh2(xu0), xh1 = tanh2(xu1);
            v2f xd0 = f1_00*xh0 + f1_01*xh1 + fb1_0;
            v2f xd1 = f1_10*xh0 + f1_11*xh1 + fb1_1;
            ox[j] = make_float4(xd0.x, xd1.x, xd0.y, xd1.y);
        }
    }
}

extern "C" void kernel_launch(void* const* d_in, const int* in_sizes, int n_in,
                              void* d_out, int out_size, void* d_ws, size_t ws_size,
                              hipStream_t stream) {
    const float* inp = (const float*)d_in[1];
    const int K = in_sizes[1]/6;
    int nv4 = K >> 1;

    const float4* q4 = (const float4*)inp;
    const float4* p4 = (const float4*)(inp + 2*(size_t)K);
    const float4* x4 = (const float4*)(inp + 4*(size_t)K);

    float* part = (float*)d_ws;                              // [21][36][NB]
    unsigned* bar = (unsigned*)(part + (size_t)(NIT+1)*36*NB);
    float c = 1.0f/(2.0f*(float)K);

    const float* t1i = (const float*)d_in[2];
    const float* b1i = (const float*)d_in[3];
    const float* t2i = (const float*)d_in[4];
    const float* b2i = (const float*)d_in[5];
    const float* invK = (const float*)d_in[6];
    const float* invKb= (const float*)d_in[7];

    float* out = (float*)d_out;
    float4* oq = (float4*)out;
    float4* op = (float4*)(out + 2*(size_t)K);
    float4* ox = (float4*)(out + 4*(size_t)K);

    hipMemsetAsync(bar, 0, sizeof(unsigned), stream);
    k_all<<<dim3(NB), dim3(TPB), 0, stream>>>(q4, p4, x4, nv4,
                                              t1i, b1i, t2i, b2i, invK, invKb,
                                              part, bar, oq, op, ox, c);
}

// Round 3
// 348.197 us; speedup vs baseline: 3.3211x; 3.3211x over previous
//
#include <hip/hip_runtime.h>

// ShootingBlockMNModel1 — single fused kernel, regular launch (graph-safe).
// Fence-free grid barrier: per-block flag array, scoped (AGENT) atomics only —
// no __threadfence (the gfx950 L2-writeback/invalidate per-thread fence storm
// was ~50us/barrier in the previous version). All cross-block data moves via
// write-through agent-scope atomic stores / bypassing agent-scope loads.
// 21 fixed-point reduce iterations (one barrier each; redundant per-block
// cross-reduce so theta needs no broadcast barrier), backfold redundant per
// block from LDS, final pass fused. q/p pinned in VGPRs (loaded once).
//
// ws (floats): part [21][36][NB] ; then unsigned flags[NB] (memset 0 per launch)

#define LR 0.25f
#define NIT 20
#define TPB 512
#define NB  256

typedef float v2f __attribute__((ext_vector_type(2)));

__device__ __forceinline__ v2f tanh2(v2f x){
    v2f e;
    e.x = __expf(x.x + x.x);
    e.y = __expf(x.y + x.y);
    v2f d = e + 1.0f;
    v2f r;
    r.x = __builtin_amdgcn_rcpf(d.x);
    r.y = __builtin_amdgcn_rcpf(d.y);
    return 1.0f - (r + r);
}

// wave64 sum via DPP on the VALU pipe; result valid in lane 63
#define DPP_ADD(x, ctrl) ((x) + __int_as_float(__builtin_amdgcn_update_dpp(0, __float_as_int(x), (ctrl), 0xF, 0xF, true)))
__device__ __forceinline__ float wave_sum64(float x){
    x = DPP_ADD(x, 0x111);   // row_shr:1
    x = DPP_ADD(x, 0x112);   // row_shr:2
    x = DPP_ADD(x, 0x114);   // row_shr:4
    x = DPP_ADD(x, 0x118);   // row_shr:8  -> lane 15+16r = row sum
    x = DPP_ADD(x, 0x142);   // row_bcast:15
    x = DPP_ADD(x, 0x143);   // row_bcast:31 -> lane 63 = total
    return x;
}

// fence-free grid barrier. arrive: flag[bid] = tgt (release, agent).
// wait: wave 0 polls all NB flags (4 per lane), agent-scope relaxed loads.
__device__ __forceinline__ void gbar(unsigned* flags, unsigned tgt,
                                     int tid, int wave, int lane){
    __syncthreads();    // drains vmcnt: this block's agent stores are visible
    if(tid == 0)
        __hip_atomic_store(flags + blockIdx.x, tgt,
                           __ATOMIC_RELEASE, __HIP_MEMORY_SCOPE_AGENT);
    if(wave == 0){
        unsigned* base = flags + lane*4;
        int guard = 0;
        for(;;){
            unsigned f0 = __hip_atomic_load(base+0, __ATOMIC_RELAXED, __HIP_MEMORY_SCOPE_AGENT);
            unsigned f1 = __hip_atomic_load(base+1, __ATOMIC_RELAXED, __HIP_MEMORY_SCOPE_AGENT);
            unsigned f2 = __hip_atomic_load(base+2, __ATOMIC_RELAXED, __HIP_MEMORY_SCOPE_AGENT);
            unsigned f3 = __hip_atomic_load(base+3, __ATOMIC_RELAXED, __HIP_MEMORY_SCOPE_AGENT);
            bool ok = (f0>=tgt) && (f1>=tgt) && (f2>=tgt) && (f3>=tgt);
            if(__all(ok)) break;
            __builtin_amdgcn_s_sleep(1);
            if(++guard > (1<<15)) break;   // watchdog: wrong-answer, never hang
        }
    }
    __syncthreads();
}

__device__ __forceinline__ void compute_grad(const float* s, const float* th,
                                             const float* ksym, const float* ksymb,
                                             float c, float* g){
    const float Ivec[4]={1.f,0.f,0.f,1.f};
    #pragma unroll
    for(int j=0;j<4;j++){
        float kv=0.f;
        #pragma unroll
        for(int m=0;m<4;m++) kv += ksym[j*4+m]*th[m];
        g[j] = kv - c*s[j];
    }
    #pragma unroll
    for(int i2=0;i2<2;i2++)
        g[4+i2] = ksymb[i2*2+0]*th[4] + ksymb[i2*2+1]*th[5] - c*s[4+i2];
    #pragma unroll
    for(int j=0;j<4;j++){
        float kv=0.f;
        #pragma unroll
        for(int m=0;m<4;m++) kv += ksym[j*4+m]*(th[6+m]-Ivec[m]);
        g[6+j] = kv - c*s[6+j];
    }
    #pragma unroll
    for(int i2=0;i2<2;i2++)
        g[10+i2] = ksymb[i2*2+0]*th[10] + ksymb[i2*2+1]*th[11] - c*s[10+i2];
}

// packed accumulate: float4 = 2 samples in v2f lanes
__device__ __forceinline__ void accum_sample2(v2f Q0, v2f Q1, v2f P0, v2f P1,
    float t1_00,float t1_01,float t1_10,float t1_11,
    float t2_00,float t2_01,float t2_10,float t2_11,float b2_0,float b2_1,
    v2f (&acc)[36]){
    v2f u0 = t2_00*Q0 + t2_01*Q1 + b2_0;
    v2f u1 = t2_10*Q0 + t2_11*Q1 + b2_1;
    v2f h0 = tanh2(u0), h1 = tanh2(u1);
    v2f s0 = 1.0f - h0*h0, s1 = 1.0f - h1*h1;
    v2f a0 = t1_00*P0 + t1_10*P1;
    v2f a1 = t1_01*P0 + t1_11*P1;
    v2f w0 = a0*s0, w1 = a1*s1;
    v2f r0 = -2.0f*(a0*h0)*s0, r1 = -2.0f*(a1*h1)*s1;
    acc[0]+=P0*h0; acc[1]+=P0*h1; acc[2]+=P1*h0; acc[3]+=P1*h1;
    acc[4]+=P0;    acc[5]+=P1;
    acc[6]+=w0*Q0; acc[7]+=w0*Q1; acc[8]+=w1*Q0; acc[9]+=w1*Q1;
    acc[10]+=w0;   acc[11]+=w1;
    v2f ps00=P0*s0, ps01=P0*s1, ps10=P1*s0, ps11=P1*s1;
    acc[12]+=ps00*Q0; acc[13]+=ps00*Q1; acc[14]+=ps01*Q0; acc[15]+=ps01*Q1;
    acc[16]+=ps10*Q0; acc[17]+=ps10*Q1; acc[18]+=ps11*Q0; acc[19]+=ps11*Q1;
    acc[20]+=ps00; acc[21]+=ps01; acc[22]+=ps10; acc[23]+=ps11;
    v2f r0q0=r0*Q0, r1q0=r1*Q0;
    acc[24]+=r0q0*Q0; acc[25]+=r0q0*Q1; acc[26]+=r0*(Q1*Q1);
    acc[27]+=r1q0*Q0; acc[28]+=r1q0*Q1; acc[29]+=r1*(Q1*Q1);
    acc[30]+=r0q0; acc[31]+=r0*Q1; acc[32]+=r1q0; acc[33]+=r1*Q1;
    acc[34]+=r0; acc[35]+=r1;
}

__device__ __forceinline__ void bk_step2(v2f Q0, v2f Q1, v2f P0, v2f P1,
    float t1_00,float t1_01,float t1_10,float t1_11,
    float t2_00,float t2_01,float t2_10,float t2_11,float b2_0,float b2_1,
    float L1_00,float L1_01,float L1_10,float L1_11,
    float L2_00,float L2_01,float L2_10,float L2_11,float lb2_0,float lb2_1,
    v2f &B0, v2f &B1){
    v2f u0 = t2_00*Q0 + t2_01*Q1 + b2_0;
    v2f u1 = t2_10*Q0 + t2_11*Q1 + b2_1;
    v2f h0 = tanh2(u0), h1 = tanh2(u1);
    v2f s0 = 1.0f - h0*h0, s1 = 1.0f - h1*h1;
    v2f a0 = t1_00*P0 + t1_10*P1;
    v2f a1 = t1_01*P0 + t1_11*P1;
    v2f w0 = a0*s0, w1 = a1*s1;
    v2f r0 = -2.0f*(a0*h0)*s0, r1 = -2.0f*(a1*h1)*s1;
    v2f lp0 = L1_00*P0 + L1_10*P1;
    v2f lp1 = L1_01*P0 + L1_11*P1;
    v2f z0 = L2_00*Q0 + L2_01*Q1 + lb2_0;
    v2f z1 = L2_10*Q0 + L2_11*Q1 + lb2_1;
    v2f m0 = lp0*s0 + r0*z0;
    v2f m1 = lp1*s1 + r1*z1;
    B0 += t2_00*m0 + t2_10*m1 + L2_00*w0 + L2_10*w1;
    B1 += t2_01*m0 + t2_11*m1 + L2_01*w0 + L2_11*w1;
}

__global__ __launch_bounds__(TPB, 2) void k_all(
    const float4* __restrict__ q4, const float4* __restrict__ p4,
    const float4* __restrict__ x4, int nv4,
    const float* __restrict__ t1i, const float* __restrict__ b1i,
    const float* __restrict__ t2i, const float* __restrict__ b2i,
    const float* __restrict__ invK, const float* __restrict__ invKb,
    float* __restrict__ part,            // [NIT+1][36][NB]
    unsigned* __restrict__ flags,        // [NB], zeroed per launch
    float4* __restrict__ oq, float4* __restrict__ op, float4* __restrict__ ox,
    float c)
{
    const int tid  = threadIdx.x;
    const int bid  = blockIdx.x;
    const int NT   = gridDim.x * TPB;
    const int gtid = bid*TPB + tid;
    const int wave = tid >> 6, lane = tid & 63;

    __shared__ float ths[12];                  // current theta
    __shared__ float thetaAll[(NIT+1)*12];     // theta stash (all iterations)
    __shared__ float sAll[(NIT+1)*36];         // sums stash (all iterations)
    __shared__ float red[TPB/64][36];
    __shared__ float ks[16], ksb[4];
    __shared__ float4 pkS[NIT*5];              // packed theta_k + lam_{k+1}

    if(tid < 16) ks[tid]  = 0.5f*(invK[tid]  + invK[(tid&3)*4 + (tid>>2)]);
    if(tid < 4)  ksb[tid] = 0.5f*(invKb[tid] + invKb[(tid&1)*2 + (tid>>1)]);
    if(tid < 12){
        float v = (tid<4)? t1i[tid] : (tid<6)? b1i[tid-4]
                : (tid<10)? t2i[tid-6] : b2i[tid-10];
        ths[tid] = v;
        thetaAll[tid] = v;
    }
    __syncthreads();

    // Pin this thread's samples in registers for the whole kernel.
    const bool fast = (nv4 == 4*NT);
    float4 qd[4], pd[4];
    if(fast){
        #pragma unroll
        for(int sl=0; sl<4; sl++){ qd[sl]=q4[gtid + sl*NT]; pd[sl]=p4[gtid + sl*NT]; }
    }

    for(int k=0; k<=NIT; k++){
        const float t1_00=ths[0], t1_01=ths[1], t1_10=ths[2], t1_11=ths[3];
        const float t2_00=ths[6], t2_01=ths[7], t2_10=ths[8], t2_11=ths[9];
        const float b2_0=ths[10], b2_1=ths[11];

        v2f acc[36];
        #pragma unroll
        for(int j=0;j<36;j++) acc[j] = (v2f){0.f, 0.f};

        if(fast){
            #pragma unroll
            for(int sl=0; sl<4; sl++){
                v2f Q0={qd[sl].x,qd[sl].z}, Q1={qd[sl].y,qd[sl].w};
                v2f P0={pd[sl].x,pd[sl].z}, P1={pd[sl].y,pd[sl].w};
                accum_sample2(Q0,Q1,P0,P1,
                    t1_00,t1_01,t1_10,t1_11,t2_00,t2_01,t2_10,t2_11,b2_0,b2_1,acc);
            }
        }else{
            for(int j = gtid; j < nv4; j += NT){
                float4 qq = q4[j], pp = p4[j];
                v2f Q0={qq.x,qq.z}, Q1={qq.y,qq.w};
                v2f P0={pp.x,pp.z}, P1={pp.y,pp.w};
                accum_sample2(Q0,Q1,P0,P1,
                    t1_00,t1_01,t1_10,t1_11,t2_00,t2_01,t2_10,t2_11,b2_0,b2_1,acc);
            }
        }

        // wave reduction on the VALU pipe, block partials
        float wres[36];
        #pragma unroll
        for(int j=0;j<36;j++) wres[j] = wave_sum64(acc[j].x + acc[j].y);
        if(lane == 63){
            #pragma unroll
            for(int j=0;j<36;j++) red[wave][j] = wres[j];
        }
        __syncthreads();
        if(tid < 36){
            float sum = 0.f;
            #pragma unroll
            for(int w=0; w<TPB/64; w++) sum += red[w][tid];
            // device-coherent write-through store (no fence needed)
            __hip_atomic_store(part + (size_t)k*36*NB + tid*NB + bid, sum,
                               __ATOMIC_RELAXED, __HIP_MEMORY_SCOPE_AGENT);
        }

        gbar(flags, (unsigned)(k+1), tid, wave, lane);

        // redundant cross-block reduce into this block's LDS (no 2nd barrier)
        {
            float pv[5];
            #pragma unroll
            for(int i=0;i<5;i++){
                int j = wave + i*(TPB/64);
                if(j < 36){
                    float* base = part + (size_t)k*36*NB + (size_t)j*NB;
                    pv[i] = __hip_atomic_load(base+lane,     __ATOMIC_RELAXED, __HIP_MEMORY_SCOPE_AGENT)
                          + __hip_atomic_load(base+lane+64,  __ATOMIC_RELAXED, __HIP_MEMORY_SCOPE_AGENT)
                          + __hip_atomic_load(base+lane+128, __ATOMIC_RELAXED, __HIP_MEMORY_SCOPE_AGENT)
                          + __hip_atomic_load(base+lane+192, __ATOMIC_RELAXED, __HIP_MEMORY_SCOPE_AGENT);
                }else pv[i] = 0.f;
            }
            #pragma unroll
            for(int i=0;i<5;i++){
                int j = wave + i*(TPB/64);
                if(j < 36){
                    float s = wave_sum64(pv[i]);
                    if(lane == 63) sAll[k*36 + j] = s;
                }
            }
        }
        __syncthreads();

        if(k < NIT){
            if(tid == 0){
                float g[12];
                compute_grad(sAll + k*36, thetaAll + k*12, ks, ksb, c, g);
                #pragma unroll
                for(int j=0;j<12;j++){
                    float t = thetaAll[k*12+j] - LR*g[j];
                    ths[j] = t;
                    thetaAll[(k+1)*12+j] = t;
                }
            }
            __syncthreads();
        }
    }

    // backfold: serial 12-dim adjoint recursion, redundant per block from LDS
    if(tid == 0){
        float lv[12];
        compute_grad(sAll + NIT*36, thetaAll + NIT*12, ks, ksb, c, lv);
        for(int k=NIT-1;k>=0;k--){
            const float* s = sAll + k*36;
            const float* T = thetaAll + k*12;
            float* P = (float*)&pkS[k*5];
            P[0]=T[0]; P[1]=T[1]; P[2]=T[2]; P[3]=T[3];
            P[4]=T[6]; P[5]=T[7]; P[6]=T[8]; P[7]=T[9];
            P[8]=T[10]; P[9]=T[11];
            P[10]=lv[0]; P[11]=lv[1]; P[12]=lv[2]; P[13]=lv[3];
            P[14]=lv[6]; P[15]=lv[7]; P[16]=lv[8]; P[17]=lv[9];
            P[18]=lv[10]; P[19]=lv[11];
            float H[12];
            for(int a=0;a<2;a++)for(int b=0;b<2;b++){
                int j=a*2+b;
                float data = s[12+a*4+b*2+0]*lv[6+b*2+0]
                           + s[12+a*4+b*2+1]*lv[6+b*2+1]
                           + s[20+a*2+b]*lv[10+b];
                float kv=0.f;
                for(int m=0;m<4;m++) kv += ks[j*4+m]*lv[m];
                H[j]=kv - c*data;
            }
            H[4] = ksb[0]*lv[4] + ksb[1]*lv[5];
            H[5] = ksb[2]*lv[4] + ksb[3]*lv[5];
            for(int cc=0;cc<2;cc++)for(int d=0;d<2;d++){
                int j=cc*2+d;
                float term1 = lv[0+cc]*s[12+0*4+cc*2+d] + lv[2+cc]*s[12+1*4+cc*2+d];
                float term2 = lv[6+cc*2+0]*s[24+cc*3+(0+d)] + lv[6+cc*2+1]*s[24+cc*3+(1+d)];
                float term3 = lv[10+cc]*s[30+cc*2+d];
                float kv=0.f;
                for(int m=0;m<4;m++) kv += ks[j*4+m]*lv[6+m];
                H[6+j]=kv - c*(term1+term2+term3);
            }
            for(int cc=0;cc<2;cc++){
                float z1 = lv[0+cc]*s[20+0*2+cc] + lv[2+cc]*s[20+1*2+cc];
                float z2 = lv[6+cc*2+0]*s[30+cc*2+0] + lv[6+cc*2+1]*s[30+cc*2+1];
                float z3 = lv[10+cc]*s[34+cc];
                float kv = ksb[cc*2+0]*lv[10] + ksb[cc*2+1]*lv[11];
                H[10+cc]=kv - c*(z1+z2+z3);
            }
            for(int j=0;j<12;j++) lv[j] -= LR*H[j];
        }
    }
    __syncthreads();

    // final phase: theta row 20 + pk from LDS, q/p still in registers
    const float* T20 = thetaAll + NIT*12;
    const float f1_00=T20[0], f1_01=T20[1], f1_10=T20[2], f1_11=T20[3];
    const float fb1_0=T20[4], fb1_1=T20[5];
    const float f2_00=T20[6], f2_01=T20[7], f2_10=T20[8], f2_11=T20[9];
    const float fb2_0=T20[10], fb2_1=T20[11];

    if(fast){
        v2f Q0r[4],Q1r[4],P0r[4],P1r[4],B0r[4],B1r[4];
        #pragma unroll
        for(int sl=0; sl<4; sl++){
            Q0r[sl]=(v2f){qd[sl].x,qd[sl].z}; Q1r[sl]=(v2f){qd[sl].y,qd[sl].w};
            P0r[sl]=(v2f){pd[sl].x,pd[sl].z}; P1r[sl]=(v2f){pd[sl].y,pd[sl].w};
            B0r[sl]=(v2f){0.f,0.f}; B1r[sl]=(v2f){0.f,0.f};
        }
        for(int k=0;k<NIT;k++){
            float4 P0=pkS[k*5+0], P1=pkS[k*5+1], P2=pkS[k*5+2], P3=pkS[k*5+3], P4v=pkS[k*5+4];
            float t1_00=P0.x,t1_01=P0.y,t1_10=P0.z,t1_11=P0.w;
            float t2_00=P1.x,t2_01=P1.y,t2_10=P1.z,t2_11=P1.w;
            float b2_0=P2.x,b2_1=P2.y;
            float L1_00=P2.z,L1_01=P2.w,L1_10=P3.x,L1_11=P3.y;
            float L2_00=P3.z,L2_01=P3.w,L2_10=P4v.x,L2_11=P4v.y,lb2_0=P4v.z,lb2_1=P4v.w;
            #pragma unroll
            for(int sl=0; sl<4; sl++)
                bk_step2(Q0r[sl],Q1r[sl],P0r[sl],P1r[sl],
                    t1_00,t1_01,t1_10,t1_11,t2_00,t2_01,t2_10,t2_11,b2_0,b2_1,
                    L1_00,L1_01,L1_10,L1_11,L2_00,L2_01,L2_10,L2_11,lb2_0,lb2_1,
                    B0r[sl],B1r[sl]);
        }
        #pragma unroll
        for(int sl=0; sl<4; sl++){
            int j = gtid + sl*NT;
            v2f Q0=Q0r[sl], Q1=Q1r[sl], P0=P0r[sl], P1=P1r[sl];
            v2f Bs0=B0r[sl], Bs1=B1r[sl];
            v2f u0 = f2_00*Q0 + f2_01*Q1 + fb2_0;
            v2f u1 = f2_10*Q0 + f2_11*Q1 + fb2_1;
            v2f h0 = tanh2(u0), h1 = tanh2(u1);
            v2f s0 = 1.0f - h0*h0, s1 = 1.0f - h1*h1;
            v2f a0 = f1_00*P0 + f1_10*P1;
            v2f a1 = f1_01*P0 + f1_11*P1;
            v2f w0 = a0*s0, w1 = a1*s1;
            v2f dq0 = f1_00*h0 + f1_01*h1 + fb1_0;
            v2f dq1 = f1_10*h0 + f1_11*h1 + fb1_1;
            v2f dp0 = c*(LR*Bs0 - (f2_00*w0 + f2_10*w1));
            v2f dp1 = c*(LR*Bs1 - (f2_01*w0 + f2_11*w1));
            oq[j] = make_float4(dq0.x, dq1.x, dq0.y, dq1.y);
            op[j] = make_float4(dp0.x, dp1.x, dp0.y, dp1.y);
            float4 xx = x4[j];
            v2f X0={xx.x,xx.z}, X1={xx.y,xx.w};
            v2f xu0 = f2_00*X0 + f2_01*X1 + fb2_0;
            v2f xu1 = f2_10*X0 + f2_11*X1 + fb2_1;
            v2f xh0 = tanh2(xu0), xh1 = tanh2(xu1);
            v2f xd0 = f1_00*xh0 + f1_01*xh1 + fb1_0;
            v2f xd1 = f1_10*xh0 + f1_11*xh1 + fb1_1;
            ox[j] = make_float4(xd0.x, xd1.x, xd0.y, xd1.y);
        }
    }else{
        for(int j = gtid; j < nv4; j += NT){
            float4 qq=q4[j], pp=p4[j];
            v2f Q0={qq.x,qq.z}, Q1={qq.y,qq.w};
            v2f P0={pp.x,pp.z}, P1={pp.y,pp.w};
            v2f Bs0={0.f,0.f}, Bs1={0.f,0.f};
            for(int k=0;k<NIT;k++){
                float4 P0v=pkS[k*5+0], P1v=pkS[k*5+1], P2v=pkS[k*5+2], P3v=pkS[k*5+3], P4v=pkS[k*5+4];
                bk_step2(Q0,Q1,P0,P1,
                    P0v.x,P0v.y,P0v.z,P0v.w, P1v.x,P1v.y,P1v.z,P1v.w, P2v.x,P2v.y,
                    P2v.z,P2v.w,P3v.x,P3v.y, P3v.z,P3v.w,P4v.x,P4v.y,P4v.z,P4v.w,
                    Bs0,Bs1);
            }
            v2f u0 = f2_00*Q0 + f2_01*Q1 + fb2_0;
            v2f u1 = f2_10*Q0 + f2_11*Q1 + fb2_1;
            v2f h0 = tanh2(u0), h1 = tanh2(u1);
            v2f s0 = 1.0f - h0*h0, s1 = 1.0f - h1*h1;
            v2f a0 = f1_00*P0 + f1_10*P1;
            v2f a1 = f1_01*P0 + f1_11*P1;
            v2f w0 = a0*s0, w1 = a1*s1;
            v2f dq0 = f1_00*h0 + f1_01*h1 + fb1_0;
            v2f dq1 = f1_10*h0 + f1_11*h1 + fb1_1;
            v2f dp0 = c*(LR*Bs0 - (f2_00*w0 + f2_10*w1));
            v2f dp1 = c*(LR*Bs1 - (f2_01*w0 + f2_11*w1));
            oq[j] = make_float4(dq0.x, dq1.x, dq0.y, dq1.y);
            op[j] = make_float4(dp0.x, dp1.x, dp0.y, dp1.y);
            float4 xx = x4[j];
            v2f X0={xx.x,xx.z}, X1={xx.y,xx.w};
            v2f xu0 = f2_00*X0 + f2_01*X1 + fb2_0;
            v2f xu1 = f2_10*X0 + f2_11*X1 + fb2_1;
            v2f xh0 = tanh2(xu0), xh1 = tanh2(xu1);
            v2f xd0 = f1_00*xh0 + f1_01*xh1 + fb1_0;
            v2f xd1 = f1_10*xh0 + f1_11*xh1 + fb1_1;
            ox[j] = make_float4(xd0.x, xd1.x, xd0.y, xd1.y);
        }
    }
}

extern "C" void kernel_launch(void* const* d_in, const int* in_sizes, int n_in,
                              void* d_out, int out_size, void* d_ws, size_t ws_size,
                              hipStream_t stream) {
    const float* inp = (const float*)d_in[1];
    const int K = in_sizes[1]/6;
    int nv4 = K >> 1;

    const float4* q4 = (const float4*)inp;
    const float4* p4 = (const float4*)(inp + 2*(size_t)K);
    const float4* x4 = (const float4*)(inp + 4*(size_t)K);

    float* part = (float*)d_ws;                              // [21][36][NB]
    unsigned* flags = (unsigned*)(part + (size_t)(NIT+1)*36*NB); // [NB]
    float c = 1.0f/(2.0f*(float)K);

    const float* t1i = (const float*)d_in[2];
    const float* b1i = (const float*)d_in[3];
    const float* t2i = (const float*)d_in[4];
    const float* b2i = (const float*)d_in[5];
    const float* invK = (const float*)d_in[6];
    const float* invKb= (const float*)d_in[7];

    float* out = (float*)d_out;
    float4* oq = (float4*)out;
    float4* op = (float4*)(out + 2*(size_t)K);
    float4* ox = (float4*)(out + 4*(size_t)K);

    hipMemsetAsync(flags, 0, NB*sizeof(unsigned), stream);
    k_all<<<dim3(NB), dim3(TPB), 0, stream>>>(q4, p4, x4, nv4,
                                              t1i, b1i, t2i, b2i, invK, invKb,
                                              part, flags, oq, op, ox, c);
}

// Round 4
// 325.563 us; speedup vs baseline: 3.5520x; 1.0695x over previous
//
#include <hip/hip_runtime.h>

// ShootingBlockMNModel1 — single fused kernel, regular launch (graph-safe).
// Single-reducer grid sync: every block stores 36 partials + arrival flag
// (agent scope, fence-free); block 0 alone polls arrivals, gathers 36x256
// partials, computes the theta update, and broadcasts {sums[36], theta[12],
// flag} in one 256B slot per iteration. Other blocks poll one dword and read
// 48 floats — no 9.4MB/iter all-to-all re-read. Backfold redundant per block
// from LDS; final pass fused; q/p pinned in VGPRs (loaded once).
//
// ws: part [21][36][NB] floats ; flags[NB] u32 ; bcast[21][64] floats
//     (flags+bcast memset to 0 per launch, 6400 B)

#define LR 0.25f
#define NIT 20
#define TPB 512
#define NB  256

typedef float v2f __attribute__((ext_vector_type(2)));

#define AG_LD(p)    __hip_atomic_load((p),  __ATOMIC_RELAXED, __HIP_MEMORY_SCOPE_AGENT)
#define AG_ST(p,v)  __hip_atomic_store((p), (v), __ATOMIC_RELAXED, __HIP_MEMORY_SCOPE_AGENT)
#define AG_ST_REL(p,v) __hip_atomic_store((p), (v), __ATOMIC_RELEASE, __HIP_MEMORY_SCOPE_AGENT)

__device__ __forceinline__ v2f tanh2(v2f x){
    v2f e;
    e.x = __expf(x.x + x.x);
    e.y = __expf(x.y + x.y);
    v2f d = e + 1.0f;
    v2f r;
    r.x = __builtin_amdgcn_rcpf(d.x);
    r.y = __builtin_amdgcn_rcpf(d.y);
    return 1.0f - (r + r);
}

// wave64 sum via DPP on the VALU pipe; result valid in lane 63
#define DPP_ADD(x, ctrl) ((x) + __int_as_float(__builtin_amdgcn_update_dpp(0, __float_as_int(x), (ctrl), 0xF, 0xF, true)))
__device__ __forceinline__ float wave_sum64(float x){
    x = DPP_ADD(x, 0x111);   // row_shr:1
    x = DPP_ADD(x, 0x112);   // row_shr:2
    x = DPP_ADD(x, 0x114);   // row_shr:4
    x = DPP_ADD(x, 0x118);   // row_shr:8  -> lane 15+16r = row sum
    x = DPP_ADD(x, 0x142);   // row_bcast:15
    x = DPP_ADD(x, 0x143);   // row_bcast:31 -> lane 63 = total
    return x;
}

__device__ __forceinline__ void compute_grad(const float* s, const float* th,
                                             const float* ksym, const float* ksymb,
                                             float c, float* g){
    const float Ivec[4]={1.f,0.f,0.f,1.f};
    #pragma unroll
    for(int j=0;j<4;j++){
        float kv=0.f;
        #pragma unroll
        for(int m=0;m<4;m++) kv += ksym[j*4+m]*th[m];
        g[j] = kv - c*s[j];
    }
    #pragma unroll
    for(int i2=0;i2<2;i2++)
        g[4+i2] = ksymb[i2*2+0]*th[4] + ksymb[i2*2+1]*th[5] - c*s[4+i2];
    #pragma unroll
    for(int j=0;j<4;j++){
        float kv=0.f;
        #pragma unroll
        for(int m=0;m<4;m++) kv += ksym[j*4+m]*(th[6+m]-Ivec[m]);
        g[6+j] = kv - c*s[6+j];
    }
    #pragma unroll
    for(int i2=0;i2<2;i2++)
        g[10+i2] = ksymb[i2*2+0]*th[10] + ksymb[i2*2+1]*th[11] - c*s[10+i2];
}

// packed accumulate: float4 = 2 samples in v2f lanes
__device__ __forceinline__ void accum_sample2(v2f Q0, v2f Q1, v2f P0, v2f P1,
    float t1_00,float t1_01,float t1_10,float t1_11,
    float t2_00,float t2_01,float t2_10,float t2_11,float b2_0,float b2_1,
    v2f (&acc)[36]){
    v2f u0 = t2_00*Q0 + t2_01*Q1 + b2_0;
    v2f u1 = t2_10*Q0 + t2_11*Q1 + b2_1;
    v2f h0 = tanh2(u0), h1 = tanh2(u1);
    v2f s0 = 1.0f - h0*h0, s1 = 1.0f - h1*h1;
    v2f a0 = t1_00*P0 + t1_10*P1;
    v2f a1 = t1_01*P0 + t1_11*P1;
    v2f w0 = a0*s0, w1 = a1*s1;
    v2f r0 = -2.0f*(a0*h0)*s0, r1 = -2.0f*(a1*h1)*s1;
    acc[0]+=P0*h0; acc[1]+=P0*h1; acc[2]+=P1*h0; acc[3]+=P1*h1;
    acc[4]+=P0;    acc[5]+=P1;
    acc[6]+=w0*Q0; acc[7]+=w0*Q1; acc[8]+=w1*Q0; acc[9]+=w1*Q1;
    acc[10]+=w0;   acc[11]+=w1;
    v2f ps00=P0*s0, ps01=P0*s1, ps10=P1*s0, ps11=P1*s1;
    acc[12]+=ps00*Q0; acc[13]+=ps00*Q1; acc[14]+=ps01*Q0; acc[15]+=ps01*Q1;
    acc[16]+=ps10*Q0; acc[17]+=ps10*Q1; acc[18]+=ps11*Q0; acc[19]+=ps11*Q1;
    acc[20]+=ps00; acc[21]+=ps01; acc[22]+=ps10; acc[23]+=ps11;
    v2f r0q0=r0*Q0, r1q0=r1*Q0;
    acc[24]+=r0q0*Q0; acc[25]+=r0q0*Q1; acc[26]+=r0*(Q1*Q1);
    acc[27]+=r1q0*Q0; acc[28]+=r1q0*Q1; acc[29]+=r1*(Q1*Q1);
    acc[30]+=r0q0; acc[31]+=r0*Q1; acc[32]+=r1q0; acc[33]+=r1*Q1;
    acc[34]+=r0; acc[35]+=r1;
}

__device__ __forceinline__ void bk_step2(v2f Q0, v2f Q1, v2f P0, v2f P1,
    float t1_00,float t1_01,float t1_10,float t1_11,
    float t2_00,float t2_01,float t2_10,float t2_11,float b2_0,float b2_1,
    float L1_00,float L1_01,float L1_10,float L1_11,
    float L2_00,float L2_01,float L2_10,float L2_11,float lb2_0,float lb2_1,
    v2f &B0, v2f &B1){
    v2f u0 = t2_00*Q0 + t2_01*Q1 + b2_0;
    v2f u1 = t2_10*Q0 + t2_11*Q1 + b2_1;
    v2f h0 = tanh2(u0), h1 = tanh2(u1);
    v2f s0 = 1.0f - h0*h0, s1 = 1.0f - h1*h1;
    v2f a0 = t1_00*P0 + t1_10*P1;
    v2f a1 = t1_01*P0 + t1_11*P1;
    v2f w0 = a0*s0, w1 = a1*s1;
    v2f r0 = -2.0f*(a0*h0)*s0, r1 = -2.0f*(a1*h1)*s1;
    v2f lp0 = L1_00*P0 + L1_10*P1;
    v2f lp1 = L1_01*P0 + L1_11*P1;
    v2f z0 = L2_00*Q0 + L2_01*Q1 + lb2_0;
    v2f z1 = L2_10*Q0 + L2_11*Q1 + lb2_1;
    v2f m0 = lp0*s0 + r0*z0;
    v2f m1 = lp1*s1 + r1*z1;
    B0 += t2_00*m0 + t2_10*m1 + L2_00*w0 + L2_10*w1;
    B1 += t2_01*m0 + t2_11*m1 + L2_01*w0 + L2_11*w1;
}

__global__ __launch_bounds__(TPB, 2) void k_all(
    const float4* __restrict__ q4, const float4* __restrict__ p4,
    const float4* __restrict__ x4, int nv4,
    const float* __restrict__ t1i, const float* __restrict__ b1i,
    const float* __restrict__ t2i, const float* __restrict__ b2i,
    const float* __restrict__ invK, const float* __restrict__ invKb,
    float* __restrict__ part,            // [NIT+1][36][NB]
    unsigned* __restrict__ flags,        // [NB], zeroed per launch
    float* __restrict__ bcast,           // [NIT+1][64], zeroed per launch
    float4* __restrict__ oq, float4* __restrict__ op, float4* __restrict__ ox,
    float c)
{
    const int tid  = threadIdx.x;
    const int bid  = blockIdx.x;
    const int NT   = gridDim.x * TPB;
    const int gtid = bid*TPB + tid;
    const int wave = tid >> 6, lane = tid & 63;

    __shared__ float ths[12];                  // current theta
    __shared__ float thetaAll[(NIT+1)*12];     // theta stash (all iterations)
    __shared__ float sAll[(NIT+1)*36];         // sums stash (all iterations)
    __shared__ float red[TPB/64][36];
    __shared__ float ks[16], ksb[4];
    __shared__ float4 pkS[NIT*5];              // packed theta_k + lam_{k+1}

    if(tid < 16) ks[tid]  = 0.5f*(invK[tid]  + invK[(tid&3)*4 + (tid>>2)]);
    if(tid < 4)  ksb[tid] = 0.5f*(invKb[tid] + invKb[(tid&1)*2 + (tid>>1)]);
    if(tid < 12){
        float v = (tid<4)? t1i[tid] : (tid<6)? b1i[tid-4]
                : (tid<10)? t2i[tid-6] : b2i[tid-10];
        ths[tid] = v;
        thetaAll[tid] = v;
    }
    __syncthreads();

    // Pin this thread's samples in registers for the whole kernel.
    const bool fast = (nv4 == 4*NT);
    float4 qd[4], pd[4];
    if(fast){
        #pragma unroll
        for(int sl=0; sl<4; sl++){ qd[sl]=q4[gtid + sl*NT]; pd[sl]=p4[gtid + sl*NT]; }
    }

    for(int k=0; k<=NIT; k++){
        const float t1_00=ths[0], t1_01=ths[1], t1_10=ths[2], t1_11=ths[3];
        const float t2_00=ths[6], t2_01=ths[7], t2_10=ths[8], t2_11=ths[9];
        const float b2_0=ths[10], b2_1=ths[11];

        v2f acc[36];
        #pragma unroll
        for(int j=0;j<36;j++) acc[j] = (v2f){0.f, 0.f};

        if(fast){
            #pragma unroll
            for(int sl=0; sl<4; sl++){
                v2f Q0={qd[sl].x,qd[sl].z}, Q1={qd[sl].y,qd[sl].w};
                v2f P0={pd[sl].x,pd[sl].z}, P1={pd[sl].y,pd[sl].w};
                accum_sample2(Q0,Q1,P0,P1,
                    t1_00,t1_01,t1_10,t1_11,t2_00,t2_01,t2_10,t2_11,b2_0,b2_1,acc);
            }
        }else{
            for(int j = gtid; j < nv4; j += NT){
                float4 qq = q4[j], pp = p4[j];
                v2f Q0={qq.x,qq.z}, Q1={qq.y,qq.w};
                v2f P0={pp.x,pp.z}, P1={pp.y,pp.w};
                accum_sample2(Q0,Q1,P0,P1,
                    t1_00,t1_01,t1_10,t1_11,t2_00,t2_01,t2_10,t2_11,b2_0,b2_1,acc);
            }
        }

        // wave reduction (VALU pipe), then block partial store + arrival flag
        float wres[36];
        #pragma unroll
        for(int j=0;j<36;j++) wres[j] = wave_sum64(acc[j].x + acc[j].y);
        if(lane == 63){
            #pragma unroll
            for(int j=0;j<36;j++) red[wave][j] = wres[j];
        }
        __syncthreads();
        if(tid < 36){
            float sum = 0.f;
            #pragma unroll
            for(int w=0; w<TPB/64; w++) sum += red[w][tid];
            AG_ST(part + (size_t)k*36*NB + tid*NB + bid, sum);
        }
        if(tid == 0)
            AG_ST_REL(flags + bid, (unsigned)(k+1));   // wave0: vmcnt-drains lanes 0..35's stores

        float* bc = bcast + (size_t)k*64;
        unsigned* bcflag = (unsigned*)(bc + 63);

        if(bid == 0){
            // wait for all 256 arrival flags
            if(wave == 0){
                unsigned* base = flags + lane*4;
                int guard = 0;
                for(;;){
                    unsigned f0=AG_LD(base+0), f1=AG_LD(base+1),
                             f2=AG_LD(base+2), f3=AG_LD(base+3);
                    unsigned tgt = (unsigned)(k+1);
                    bool ok = (f0>=tgt)&&(f1>=tgt)&&(f2>=tgt)&&(f3>=tgt);
                    if(__all(ok)) break;
                    __builtin_amdgcn_s_sleep(1);
                    if(++guard > (1<<16)) break;   // watchdog: wrong-answer, never hang
                }
            }
            __syncthreads();
            // gather 36x256 partials: wave w -> segments w, w+8, ...
            for(int s = wave; s < 36; s += TPB/64){
                float* base = part + (size_t)k*36*NB + (size_t)s*NB;
                float v = AG_LD(base+lane) + AG_LD(base+lane+64)
                        + AG_LD(base+lane+128) + AG_LD(base+lane+192);
                v = wave_sum64(v);
                if(lane == 63) sAll[k*36 + s] = v;
            }
            __syncthreads();
            if(tid == 0 && k < NIT){
                float g[12];
                compute_grad(sAll + k*36, thetaAll + k*12, ks, ksb, c, g);
                #pragma unroll
                for(int j=0;j<12;j++){
                    float t = thetaAll[k*12+j] - LR*g[j];
                    ths[j] = t;
                    thetaAll[(k+1)*12+j] = t;
                }
            }
            __syncthreads();
            // broadcast sums + next theta + flag (wave 0 only: release orders stores)
            if(wave == 0){
                if(lane < 36)                 AG_ST(bc + lane, sAll[k*36 + lane]);
                else if(lane < 48 && k < NIT) AG_ST(bc + lane, ths[lane-36]);
                if(lane == 0) AG_ST_REL(bcflag, (unsigned)(k+1));
            }
            // ths/thetaAll/sAll already up to date in LDS; continue
        }else{
            // poll the single broadcast flag, then read 48 floats
            if(wave == 0){
                int guard = 0;
                for(;;){
                    unsigned f = AG_LD(bcflag);
                    if(f >= (unsigned)(k+1)) break;
                    __builtin_amdgcn_s_sleep(1);
                    if(++guard > (1<<17)) break;   // watchdog
                }
                if(lane < 36) sAll[k*36 + lane] = AG_LD(bc + lane);
                else if(lane < 48 && k < NIT){
                    float t = AG_LD(bc + lane);
                    ths[lane-36] = t;
                    thetaAll[(k+1)*12 + (lane-36)] = t;
                }
            }
            __syncthreads();
        }
    }

    // backfold: serial 12-dim adjoint recursion, redundant per block from LDS
    if(tid == 0){
        float lv[12];
        compute_grad(sAll + NIT*36, thetaAll + NIT*12, ks, ksb, c, lv);
        for(int k=NIT-1;k>=0;k--){
            const float* s = sAll + k*36;
            const float* T = thetaAll + k*12;
            float* P = (float*)&pkS[k*5];
            P[0]=T[0]; P[1]=T[1]; P[2]=T[2]; P[3]=T[3];
            P[4]=T[6]; P[5]=T[7]; P[6]=T[8]; P[7]=T[9];
            P[8]=T[10]; P[9]=T[11];
            P[10]=lv[0]; P[11]=lv[1]; P[12]=lv[2]; P[13]=lv[3];
            P[14]=lv[6]; P[15]=lv[7]; P[16]=lv[8]; P[17]=lv[9];
            P[18]=lv[10]; P[19]=lv[11];
            float H[12];
            for(int a=0;a<2;a++)for(int b=0;b<2;b++){
                int j=a*2+b;
                float data = s[12+a*4+b*2+0]*lv[6+b*2+0]
                           + s[12+a*4+b*2+1]*lv[6+b*2+1]
                           + s[20+a*2+b]*lv[10+b];
                float kv=0.f;
                for(int m=0;m<4;m++) kv += ks[j*4+m]*lv[m];
                H[j]=kv - c*data;
            }
            H[4] = ksb[0]*lv[4] + ksb[1]*lv[5];
            H[5] = ksb[2]*lv[4] + ksb[3]*lv[5];
            for(int cc=0;cc<2;cc++)for(int d=0;d<2;d++){
                int j=cc*2+d;
                float term1 = lv[0+cc]*s[12+0*4+cc*2+d] + lv[2+cc]*s[12+1*4+cc*2+d];
                float term2 = lv[6+cc*2+0]*s[24+cc*3+(0+d)] + lv[6+cc*2+1]*s[24+cc*3+(1+d)];
                float term3 = lv[10+cc]*s[30+cc*2+d];
                float kv=0.f;
                for(int m=0;m<4;m++) kv += ks[j*4+m]*lv[6+m];
                H[6+j]=kv - c*(term1+term2+term3);
            }
            for(int cc=0;cc<2;cc++){
                float z1 = lv[0+cc]*s[20+0*2+cc] + lv[2+cc]*s[20+1*2+cc];
                float z2 = lv[6+cc*2+0]*s[30+cc*2+0] + lv[6+cc*2+1]*s[30+cc*2+1];
                float z3 = lv[10+cc]*s[34+cc];
                float kv = ksb[cc*2+0]*lv[10] + ksb[cc*2+1]*lv[11];
                H[10+cc]=kv - c*(z1+z2+z3);
            }
            for(int j=0;j<12;j++) lv[j] -= LR*H[j];
        }
    }
    __syncthreads();

    // final phase: theta row 20 + pk from LDS, q/p still in registers
    const float* T20 = thetaAll + NIT*12;
    const float f1_00=T20[0], f1_01=T20[1], f1_10=T20[2], f1_11=T20[3];
    const float fb1_0=T20[4], fb1_1=T20[5];
    const float f2_00=T20[6], f2_01=T20[7], f2_10=T20[8], f2_11=T20[9];
    const float fb2_0=T20[10], fb2_1=T20[11];

    if(fast){
        v2f Q0r[4],Q1r[4],P0r[4],P1r[4],B0r[4],B1r[4];
        #pragma unroll
        for(int sl=0; sl<4; sl++){
            Q0r[sl]=(v2f){qd[sl].x,qd[sl].z}; Q1r[sl]=(v2f){qd[sl].y,qd[sl].w};
            P0r[sl]=(v2f){pd[sl].x,pd[sl].z}; P1r[sl]=(v2f){pd[sl].y,pd[sl].w};
            B0r[sl]=(v2f){0.f,0.f}; B1r[sl]=(v2f){0.f,0.f};
        }
        for(int k=0;k<NIT;k++){
            float4 P0=pkS[k*5+0], P1=pkS[k*5+1], P2=pkS[k*5+2], P3=pkS[k*5+3], P4v=pkS[k*5+4];
            float t1_00=P0.x,t1_01=P0.y,t1_10=P0.z,t1_11=P0.w;
            float t2_00=P1.x,t2_01=P1.y,t2_10=P1.z,t2_11=P1.w;
            float b2_0=P2.x,b2_1=P2.y;
            float L1_00=P2.z,L1_01=P2.w,L1_10=P3.x,L1_11=P3.y;
            float L2_00=P3.z,L2_01=P3.w,L2_10=P4v.x,L2_11=P4v.y,lb2_0=P4v.z,lb2_1=P4v.w;
            #pragma unroll
            for(int sl=0; sl<4; sl++)
                bk_step2(Q0r[sl],Q1r[sl],P0r[sl],P1r[sl],
                    t1_00,t1_01,t1_10,t1_11,t2_00,t2_01,t2_10,t2_11,b2_0,b2_1,
                    L1_00,L1_01,L1_10,L1_11,L2_00,L2_01,L2_10,L2_11,lb2_0,lb2_1,
                    B0r[sl],B1r[sl]);
        }
        #pragma unroll
        for(int sl=0; sl<4; sl++){
            int j = gtid + sl*NT;
            v2f Q0=Q0r[sl], Q1=Q1r[sl], P0=P0r[sl], P1=P1r[sl];
            v2f Bs0=B0r[sl], Bs1=B1r[sl];
            v2f u0 = f2_00*Q0 + f2_01*Q1 + fb2_0;
            v2f u1 = f2_10*Q0 + f2_11*Q1 + fb2_1;
            v2f h0 = tanh2(u0), h1 = tanh2(u1);
            v2f s0 = 1.0f - h0*h0, s1 = 1.0f - h1*h1;
            v2f a0 = f1_00*P0 + f1_10*P1;
            v2f a1 = f1_01*P0 + f1_11*P1;
            v2f w0 = a0*s0, w1 = a1*s1;
            v2f dq0 = f1_00*h0 + f1_01*h1 + fb1_0;
            v2f dq1 = f1_10*h0 + f1_11*h1 + fb1_1;
            v2f dp0 = c*(LR*Bs0 - (f2_00*w0 + f2_10*w1));
            v2f dp1 = c*(LR*Bs1 - (f2_01*w0 + f2_11*w1));
            oq[j] = make_float4(dq0.x, dq1.x, dq0.y, dq1.y);
            op[j] = make_float4(dp0.x, dp1.x, dp0.y, dp1.y);
            float4 xx = x4[j];
            v2f X0={xx.x,xx.z}, X1={xx.y,xx.w};
            v2f xu0 = f2_00*X0 + f2_01*X1 + fb2_0;
            v2f xu1 = f2_10*X0 + f2_11*X1 + fb2_1;
            v2f xh0 = tanh2(xu0), xh1 = tanh2(xu1);
            v2f xd0 = f1_00*xh0 + f1_01*xh1 + fb1_0;
            v2f xd1 = f1_10*xh0 + f1_11*xh1 + fb1_1;
            ox[j] = make_float4(xd0.x, xd1.x, xd0.y, xd1.y);
        }
    }else{
        for(int j = gtid; j < nv4; j += NT){
            float4 qq=q4[j], pp=p4[j];
            v2f Q0={qq.x,qq.z}, Q1={qq.y,qq.w};
            v2f P0={pp.x,pp.z}, P1={pp.y,pp.w};
            v2f Bs0={0.f,0.f}, Bs1={0.f,0.f};
            for(int k=0;k<NIT;k++){
                float4 P0v=pkS[k*5+0], P1v=pkS[k*5+1], P2v=pkS[k*5+2], P3v=pkS[k*5+3], P4v=pkS[k*5+4];
                bk_step2(Q0,Q1,P0,P1,
                    P0v.x,P0v.y,P0v.z,P0v.w, P1v.x,P1v.y,P1v.z,P1v.w, P2v.x,P2v.y,
                    P2v.z,P2v.w,P3v.x,P3v.y, P3v.z,P3v.w,P4v.x,P4v.y,P4v.z,P4v.w,
                    Bs0,Bs1);
            }
            v2f u0 = f2_00*Q0 + f2_01*Q1 + fb2_0;
            v2f u1 = f2_10*Q0 + f2_11*Q1 + fb2_1;
            v2f h0 = tanh2(u0), h1 = tanh2(u1);
            v2f s0 = 1.0f - h0*h0, s1 = 1.0f - h1*h1;
            v2f a0 = f1_00*P0 + f1_10*P1;
            v2f a1 = f1_01*P0 + f1_11*P1;
            v2f w0 = a0*s0, w1 = a1*s1;
            v2f dq0 = f1_00*h0 + f1_01*h1 + fb1_0;
            v2f dq1 = f1_10*h0 + f1_11*h1 + fb1_1;
            v2f dp0 = c*(LR*Bs0 - (f2_00*w0 + f2_10*w1));
            v2f dp1 = c*(LR*Bs1 - (f2_01*w0 + f2_11*w1));
            oq[j] = make_float4(dq0.x, dq1.x, dq0.y, dq1.y);
            op[j] = make_float4(dp0.x, dp1.x, dp0.y, dp1.y);
            float4 xx = x4[j];
            v2f X0={xx.x,xx.z}, X1={xx.y,xx.w};
            v2f xu0 = f2_00*X0 + f2_01*X1 + fb2_0;
            v2f xu1 = f2_10*X0 + f2_11*X1 + fb2_1;
            v2f xh0 = tanh2(xu0), xh1 = tanh2(xu1);
            v2f xd0 = f1_00*xh0 + f1_01*xh1 + fb1_0;
            v2f xd1 = f1_10*xh0 + f1_11*xh1 + fb1_1;
            ox[j] = make_float4(xd0.x, xd1.x, xd0.y, xd1.y);
        }
    }
}

extern "C" void kernel_launch(void* const* d_in, const int* in_sizes, int n_in,
                              void* d_out, int out_size, void* d_ws, size_t ws_size,
                              hipStream_t stream) {
    const float* inp = (const float*)d_in[1];
    const int K = in_sizes[1]/6;
    int nv4 = K >> 1;

    const float4* q4 = (const float4*)inp;
    const float4* p4 = (const float4*)(inp + 2*(size_t)K);
    const float4* x4 = (const float4*)(inp + 4*(size_t)K);

    float* part = (float*)d_ws;                                  // [21][36][NB]
    unsigned* flags = (unsigned*)(part + (size_t)(NIT+1)*36*NB); // [NB]
    float* bcast = (float*)(flags + NB);                         // [21][64]
    float c = 1.0f/(2.0f*(float)K);

    const float* t1i = (const float*)d_in[2];
    const float* b1i = (const float*)d_in[3];
    const float* t2i = (const float*)d_in[4];
    const float* b2i = (const float*)d_in[5];
    const float* invK = (const float*)d_in[6];
    const float* invKb= (const float*)d_in[7];

    float* out = (float*)d_out;
    float4* oq = (float4*)out;
    float4* op = (float4*)(out + 2*(size_t)K);
    float4* ox = (float4*)(out + 4*(size_t)K);

    // zero flags + bcast (contiguous): NB u32 + 21*64 floats
    hipMemsetAsync(flags, 0, NB*sizeof(unsigned) + (NIT+1)*64*sizeof(float), stream);
    k_all<<<dim3(NB), dim3(TPB), 0, stream>>>(q4, p4, x4, nv4,
                                              t1i, b1i, t2i, b2i, invK, invKb,
                                              part, flags, bcast, oq, op, ox, c);
}